// Round 1
// 1119.972 us; speedup vs baseline: 3.0841x; 3.0841x over previous
//
#include <hip/hip_runtime.h>
#include <cstddef>

#define TSTEPS 512
#define INDIM  22
#define HDIM   64
#define NBATCH 16
#define KTOT   (INDIM + HDIM)   // 86 combined reduction dim
#define ZSTR   104              // bf16 row stride: 13*8 -> 16B-aligned frags, odd 8-chunk count breaks bank aliasing
#define HPAD   (HDIM + 4)

typedef float v4f __attribute__((ext_vector_type(4)));
typedef short v8s __attribute__((ext_vector_type(8)));

__device__ __forceinline__ float sigm(float x) { return 1.0f / (1.0f + __expf(-x)); }
__device__ __forceinline__ float tanh_fast(float x) {
    // 1 - 2/(e^{2x}+1): stable for all x
    return 1.0f - 2.0f / (__expf(2.0f * x) + 1.0f);
}
// round-to-nearest-even fp32 -> bf16
__device__ __forceinline__ unsigned short bf16_rne(float x) {
    unsigned u = __float_as_uint(x);
    u += 0x7fffu + ((u >> 16) & 1u);
    return (unsigned short)(u >> 16);
}
__device__ __forceinline__ float bf16_f(unsigned short s) {
    return __uint_as_float((unsigned)s << 16);
}

// One block = 16 batch rows for all 512 steps; 8 waves.
// Per step: gates^T[256,16] = Wall[256,96] * z[96,16] via mfma_f32_16x16x32_bf16,
// split-bf16 (hi/lo) for fp32-grade accuracy (3 MFMAs per tile, lo*lo dropped).
// Gate-rows reordered r = 4*j + g so the C-frag gives each lane all 4 gates of one
// (batch, j) cell in its 4 acc regs -> epilogue fully in-register.
// Weights stay in VGPRs (time-invariant A-frags); LDS holds only z (hi/lo bf16,
// double-buffered) + an fp32 h buffer used to transpose h into coalesced stores.
__global__ __launch_bounds__(512, 2)
void lstm_mfma(const float* __restrict__ x,     // [B, T, IN]
               const float* __restrict__ W_ih,  // [4H, IN]
               const float* __restrict__ W_hh,  // [4H, H]
               const float* __restrict__ b_ih,  // [4H]
               const float* __restrict__ b_hh,  // [4H]
               float* __restrict__ out)         // [B, T, H]
{
    __shared__ __align__(16) unsigned short zhi[2][NBATCH][ZSTR];  // 6656 B
    __shared__ __align__(16) unsigned short zlo[2][NBATCH][ZSTR];  // 6656 B
    __shared__ float hfp[2][NBATCH][HPAD];                         // 8704 B

    const int tid = threadIdx.x;
    const int l   = tid & 63;
    const int w   = tid >> 6;          // wave 0..7: gate-rows [32w, 32w+32)
    const int lr  = l & 15;            // A-row / B-col (batch) lane selector
    const int lk  = l >> 4;            // k-chunk selector (8 bf16 per chunk)
    const int bbase = blockIdx.x * NBATCH;

    // ---- weights -> registers: A-frags for 2 M-tiles x 3 K-steps, hi/lo split ----
    v8s a_hi[2][3], a_lo[2][3];
    #pragma unroll
    for (int mt = 0; mt < 2; ++mt) {
        const int row  = 32 * w + 16 * mt + lr;          // gate-row r = 4*j + g
        const int grow = (row & 3) * HDIM + (row >> 2);  // original row g*64 + j
        #pragma unroll
        for (int ks = 0; ks < 3; ++ks) {
            #pragma unroll
            for (int e = 0; e < 8; ++e) {
                const int k = 32 * ks + 8 * lk + e;
                float wv = 0.0f;
                if (k < INDIM)      wv = W_ih[grow * INDIM + k];
                else if (k < KTOT)  wv = W_hh[grow * HDIM + (k - INDIM)];
                const unsigned short hi = bf16_rne(wv);
                const unsigned short lo = bf16_rne(wv - bf16_f(hi));
                a_hi[mt][ks][e] = (short)hi;
                a_lo[mt][ks][e] = (short)lo;
            }
        }
    }
    // biases for this lane's 8 output cells (acc reg r <-> gate r)
    v4f biasv[2];
    #pragma unroll
    for (int mt = 0; mt < 2; ++mt) {
        const int jj = 8 * w + 4 * mt + lk;
        #pragma unroll
        for (int r = 0; r < 4; ++r)
            biasv[mt][r] = b_ih[r * HDIM + jj] + b_hh[r * HDIM + jj];
    }

    // ---- zero both z buffers entirely (covers h_{-1}=0 and the k>=86 pad:
    //      pad MUST be 0, not garbage, else 0*NaN pollutes the MFMA) ----
    {
        unsigned short* p1 = &zhi[0][0][0];
        unsigned short* p2 = &zlo[0][0][0];
        for (int idx = tid; idx < 2 * NBATCH * ZSTR; idx += 512) {
            p1[idx] = 0; p2[idx] = 0;
        }
    }

    // x staging: thread tid < 352 owns one (batch, in-feature) slot
    const bool hasx = (tid < NBATCH * INDIM);
    const int xb = hasx ? tid / INDIM : 0;
    const int xi = hasx ? (tid - xb * INDIM) : 0;
    const float* xp = x + (size_t)(bbase + xb) * TSTEPS * INDIM + xi;
    float xv = 0.0f;

    __syncthreads();   // zero-fill visible before x[0] staging

    if (hasx) {
        const float x0 = xp[0];
        const unsigned short hi = bf16_rne(x0);
        zhi[0][xb][xi] = hi;
        zlo[0][xb][xi] = bf16_rne(x0 - bf16_f(hi));
        xv = xp[INDIM];        // prefetch x[1]
        xp += 2 * INDIM;       // -> x[2]
    }

    // coalesced out writeback mapping: 32 lanes x float2 = one 256B batch-row
    const int ob = tid >> 5;           // batch 0..15
    const int oc = (tid & 31) * 2;     // h-offset
    float* op = out + (size_t)(bbase + ob) * TSTEPS * HDIM + oc;

    float c[2] = {0.0f, 0.0f};
    const v4f vzero = {0.0f, 0.0f, 0.0f, 0.0f};

    for (int t = 0; t < TSTEPS; ++t) {
        const int cur = t & 1;
        const int nxt = cur ^ 1;
        __syncthreads();   // prev step's writes visible; separates from this step's reads

        // (A) coalesced global store of h[t-1] (written to hfp[nxt] last step)
        if (t) {
            const float2 hv = *(const float2*)&hfp[nxt][ob][oc];
            *(float2*)op = hv;
            op += HDIM;
        }

        // (C) stage x[t+1] into the other buffer; prefetch x[t+2] into a register
        if (hasx && t + 1 < TSTEPS) {
            const unsigned short hi = bf16_rne(xv);
            zhi[nxt][xb][xi] = hi;
            zlo[nxt][xb][xi] = bf16_rne(xv - bf16_f(hi));
        }
        if (hasx && t + 2 < TSTEPS) { xv = *xp; xp += INDIM; }

        // (B) gate GEMM: 3 independent accumulator chains per tile (depth 3)
        v4f s0[3], s1[3];
        s0[0] = biasv[0]; s0[1] = vzero; s0[2] = vzero;
        s1[0] = biasv[1]; s1[1] = vzero; s1[2] = vzero;
        #pragma unroll
        for (int ks = 0; ks < 3; ++ks) {
            const v8s bhi = *(const v8s*)&zhi[cur][lr][32 * ks + 8 * lk];
            const v8s blo = *(const v8s*)&zlo[cur][lr][32 * ks + 8 * lk];
            s0[ks] = __builtin_amdgcn_mfma_f32_16x16x32_bf16(a_hi[0][ks], bhi, s0[ks], 0, 0, 0);
            s1[ks] = __builtin_amdgcn_mfma_f32_16x16x32_bf16(a_hi[1][ks], bhi, s1[ks], 0, 0, 0);
            s0[ks] = __builtin_amdgcn_mfma_f32_16x16x32_bf16(a_hi[0][ks], blo, s0[ks], 0, 0, 0);
            s1[ks] = __builtin_amdgcn_mfma_f32_16x16x32_bf16(a_hi[1][ks], blo, s1[ks], 0, 0, 0);
            s0[ks] = __builtin_amdgcn_mfma_f32_16x16x32_bf16(a_lo[0][ks], bhi, s0[ks], 0, 0, 0);
            s1[ks] = __builtin_amdgcn_mfma_f32_16x16x32_bf16(a_lo[1][ks], bhi, s1[ks], 0, 0, 0);
        }
        const v4f acc0 = s0[0] + s0[1] + s0[2];
        const v4f acc1 = s1[0] + s1[1] + s1[2];

        // (D) epilogue: all 4 gates of each cell live in this lane's acc regs
        #pragma unroll
        for (int mt = 0; mt < 2; ++mt) {
            const v4f a = mt ? acc1 : acc0;
            const float iv = sigm(a[0]);
            const float fv = sigm(a[1]);
            const float gv = tanh_fast(a[2]);
            const float ov = sigm(a[3]);
            c[mt] = fv * c[mt] + iv * gv;
            const float hv = ov * tanh_fast(c[mt]);
            const int jj = 8 * w + 4 * mt + lk;
            const unsigned short hhi = bf16_rne(hv);
            zhi[nxt][lr][INDIM + jj] = hhi;                     // B-operand for t+1
            zlo[nxt][lr][INDIM + jj] = bf16_rne(hv - bf16_f(hhi));
            hfp[cur][lr][jj] = hv;                              // fp32 for writeback
        }
    }

    // final writeback: h[T-1] sits in hfp[(T-1)&1] = hfp[1]
    __syncthreads();
    {
        const float2 hv = *(const float2*)&hfp[1][ob][oc];
        *(float2*)op = hv;
    }
}

extern "C" void kernel_launch(void* const* d_in, const int* in_sizes, int n_in,
                              void* d_out, int out_size, void* d_ws, size_t ws_size,
                              hipStream_t stream) {
    const float* x    = (const float*)d_in[0];
    const float* W_ih = (const float*)d_in[1];
    const float* W_hh = (const float*)d_in[2];
    const float* b_ih = (const float*)d_in[3];
    const float* b_hh = (const float*)d_in[4];
    float* out = (float*)d_out;

    const int B = in_sizes[0] / (TSTEPS * INDIM);   // 4096
    const int grid = B / NBATCH;                    // 256 blocks, 1 per CU
    lstm_mfma<<<grid, 512, 0, stream>>>(x, W_ih, W_hh, b_ih, b_hh, out);
}

// Round 2
// 1114.614 us; speedup vs baseline: 3.0989x; 1.0048x over previous
//
#include <hip/hip_runtime.h>
#include <cstddef>

#define TSTEPS 512
#define INDIM  22
#define HDIM   64
#define NBATCH 16
#define KTOT   (INDIM + HDIM)   // 86 combined reduction dim
#define ZSTR   104              // bf16 row stride: 13*8 -> 16B-aligned frags, odd 8-chunk count breaks bank aliasing
#define HPAD   (HDIM + 4)

typedef float v4f __attribute__((ext_vector_type(4)));
typedef short v8s __attribute__((ext_vector_type(8)));

__device__ __forceinline__ float sigm(float x) { return 1.0f / (1.0f + __expf(-x)); }
__device__ __forceinline__ float tanh_fast(float x) {
    // 1 - 2/(e^{2x}+1): stable for all x
    return 1.0f - 2.0f / (__expf(2.0f * x) + 1.0f);
}
// round-to-nearest-even fp32 -> bf16
__device__ __forceinline__ unsigned short bf16_rne(float x) {
    unsigned u = __float_as_uint(x);
    u += 0x7fffu + ((u >> 16) & 1u);
    return (unsigned short)(u >> 16);
}
__device__ __forceinline__ float bf16_f(unsigned short s) {
    return __uint_as_float((unsigned)s << 16);
}

// Workgroup barrier WITHOUT the vmcnt(0) drain __syncthreads() would emit.
// LDS ordering (the only thing the z/hfp buffers need) is preserved by
// lgkmcnt(0) before s_barrier; global stores/loads float across steps and
// retire at bandwidth instead of serializing an HBM round-trip per step.
__device__ __forceinline__ void barrier_lds_only() {
    asm volatile("s_waitcnt lgkmcnt(0)\n\ts_barrier" ::: "memory");
}

// One block = 16 batch rows for all 512 steps; 8 waves.
// Per step: gates^T[256,16] = Wall[256,96] * z[96,16] via mfma_f32_16x16x32_bf16,
// split-bf16 (hi/lo) for fp32-grade accuracy (3 MFMAs per tile, lo*lo dropped).
// Gate-rows reordered r = 4*j + g so the C-frag gives each lane all 4 gates of one
// (batch, j) cell in its 4 acc regs -> epilogue fully in-register.
// Weights stay in VGPRs (time-invariant A-frags); LDS holds only z (hi/lo bf16,
// double-buffered) + an fp32 h buffer used to transpose h into coalesced stores.
__global__ __launch_bounds__(512, 2)
void lstm_mfma(const float* __restrict__ x,     // [B, T, IN]
               const float* __restrict__ W_ih,  // [4H, IN]
               const float* __restrict__ W_hh,  // [4H, H]
               const float* __restrict__ b_ih,  // [4H]
               const float* __restrict__ b_hh,  // [4H]
               float* __restrict__ out)         // [B, T, H]
{
    __shared__ __align__(16) unsigned short zhi[2][NBATCH][ZSTR];  // 6656 B
    __shared__ __align__(16) unsigned short zlo[2][NBATCH][ZSTR];  // 6656 B
    __shared__ float hfp[2][NBATCH][HPAD];                         // 8704 B

    const int tid = threadIdx.x;
    const int l   = tid & 63;
    const int w   = tid >> 6;          // wave 0..7: gate-rows [32w, 32w+32)
    const int lr  = l & 15;            // A-row / B-col (batch) lane selector
    const int lk  = l >> 4;            // k-chunk selector (8 bf16 per chunk)
    const int bbase = blockIdx.x * NBATCH;

    // ---- weights -> registers: A-frags for 2 M-tiles x 3 K-steps, hi/lo split ----
    v8s a_hi[2][3], a_lo[2][3];
    #pragma unroll
    for (int mt = 0; mt < 2; ++mt) {
        const int row  = 32 * w + 16 * mt + lr;          // gate-row r = 4*j + g
        const int grow = (row & 3) * HDIM + (row >> 2);  // original row g*64 + j
        #pragma unroll
        for (int ks = 0; ks < 3; ++ks) {
            #pragma unroll
            for (int e = 0; e < 8; ++e) {
                const int k = 32 * ks + 8 * lk + e;
                float wv = 0.0f;
                if (k < INDIM)      wv = W_ih[grow * INDIM + k];
                else if (k < KTOT)  wv = W_hh[grow * HDIM + (k - INDIM)];
                const unsigned short hi = bf16_rne(wv);
                const unsigned short lo = bf16_rne(wv - bf16_f(hi));
                a_hi[mt][ks][e] = (short)hi;
                a_lo[mt][ks][e] = (short)lo;
            }
        }
    }
    // biases for this lane's 8 output cells (acc reg r <-> gate r)
    v4f biasv[2];
    #pragma unroll
    for (int mt = 0; mt < 2; ++mt) {
        const int jj = 8 * w + 4 * mt + lk;
        #pragma unroll
        for (int r = 0; r < 4; ++r)
            biasv[mt][r] = b_ih[r * HDIM + jj] + b_hh[r * HDIM + jj];
    }

    // ---- zero both z buffers entirely (covers h_{-1}=0 and the k>=86 pad:
    //      pad MUST be 0, not garbage, else 0*NaN pollutes the MFMA) ----
    {
        unsigned short* p1 = &zhi[0][0][0];
        unsigned short* p2 = &zlo[0][0][0];
        for (int idx = tid; idx < 2 * NBATCH * ZSTR; idx += 512) {
            p1[idx] = 0; p2[idx] = 0;
        }
    }

    // x staging: thread tid < 352 owns one (batch, in-feature) slot
    const bool hasx = (tid < NBATCH * INDIM);
    const int xb = hasx ? tid / INDIM : 0;
    const int xi = hasx ? (tid - xb * INDIM) : 0;
    const float* xp = x + (size_t)(bbase + xb) * TSTEPS * INDIM + xi;
    float xv = 0.0f;

    __syncthreads();   // zero-fill visible before x[0] staging (full sync, once)

    if (hasx) {
        const float x0 = xp[0];
        const unsigned short hi = bf16_rne(x0);
        zhi[0][xb][xi] = hi;
        zlo[0][xb][xi] = bf16_rne(x0 - bf16_f(hi));
        xv = xp[INDIM];        // prefetch x[1]
        xp += 2 * INDIM;       // -> x[2]
    }

    // coalesced out writeback mapping: 32 lanes x float2 = one 256B batch-row
    const int ob = tid >> 5;           // batch 0..15
    const int oc = (tid & 31) * 2;     // h-offset
    float* op = out + (size_t)(bbase + ob) * TSTEPS * HDIM + oc;

    float c[2] = {0.0f, 0.0f};
    const v4f vzero = {0.0f, 0.0f, 0.0f, 0.0f};

    for (int t = 0; t < TSTEPS; ++t) {
        const int cur = t & 1;
        const int nxt = cur ^ 1;
        barrier_lds_only();   // prev step's LDS writes visible; vmcnt floats

        // (A) coalesced global store of h[t-1] (written to hfp[nxt] last step)
        if (t) {
            const float2 hv = *(const float2*)&hfp[nxt][ob][oc];
            *(float2*)op = hv;
            op += HDIM;
        }

        // (C) stage x[t+1] into the other buffer; prefetch x[t+2] into a register
        if (hasx && t + 1 < TSTEPS) {
            const unsigned short hi = bf16_rne(xv);
            zhi[nxt][xb][xi] = hi;
            zlo[nxt][xb][xi] = bf16_rne(xv - bf16_f(hi));
        }
        if (hasx && t + 2 < TSTEPS) { xv = *xp; xp += INDIM; }

        // (B) gate GEMM: 3 independent accumulator chains per tile (depth 3)
        v4f s0[3], s1[3];
        s0[0] = biasv[0]; s0[1] = vzero; s0[2] = vzero;
        s1[0] = biasv[1]; s1[1] = vzero; s1[2] = vzero;
        #pragma unroll
        for (int ks = 0; ks < 3; ++ks) {
            const v8s bhi = *(const v8s*)&zhi[cur][lr][32 * ks + 8 * lk];
            const v8s blo = *(const v8s*)&zlo[cur][lr][32 * ks + 8 * lk];
            s0[ks] = __builtin_amdgcn_mfma_f32_16x16x32_bf16(a_hi[0][ks], bhi, s0[ks], 0, 0, 0);
            s1[ks] = __builtin_amdgcn_mfma_f32_16x16x32_bf16(a_hi[1][ks], bhi, s1[ks], 0, 0, 0);
            s0[ks] = __builtin_amdgcn_mfma_f32_16x16x32_bf16(a_hi[0][ks], blo, s0[ks], 0, 0, 0);
            s1[ks] = __builtin_amdgcn_mfma_f32_16x16x32_bf16(a_hi[1][ks], blo, s1[ks], 0, 0, 0);
            s0[ks] = __builtin_amdgcn_mfma_f32_16x16x32_bf16(a_lo[0][ks], bhi, s0[ks], 0, 0, 0);
            s1[ks] = __builtin_amdgcn_mfma_f32_16x16x32_bf16(a_lo[1][ks], bhi, s1[ks], 0, 0, 0);
        }
        const v4f acc0 = s0[0] + s0[1] + s0[2];
        const v4f acc1 = s1[0] + s1[1] + s1[2];

        // (D) epilogue: all 4 gates of each cell live in this lane's acc regs
        #pragma unroll
        for (int mt = 0; mt < 2; ++mt) {
            const v4f a = mt ? acc1 : acc0;
            const float iv = sigm(a[0]);
            const float fv = sigm(a[1]);
            const float gv = tanh_fast(a[2]);
            const float ov = sigm(a[3]);
            c[mt] = fv * c[mt] + iv * gv;
            const float hv = ov * tanh_fast(c[mt]);
            const int jj = 8 * w + 4 * mt + lk;
            const unsigned short hhi = bf16_rne(hv);
            zhi[nxt][lr][INDIM + jj] = hhi;                     // B-operand for t+1
            zlo[nxt][lr][INDIM + jj] = bf16_rne(hv - bf16_f(hhi));
            hfp[cur][lr][jj] = hv;                              // fp32 for writeback
        }
    }

    // final writeback: h[T-1] sits in hfp[(T-1)&1] = hfp[1]
    __syncthreads();
    {
        const float2 hv = *(const float2*)&hfp[1][ob][oc];
        *(float2*)op = hv;
    }
}

extern "C" void kernel_launch(void* const* d_in, const int* in_sizes, int n_in,
                              void* d_out, int out_size, void* d_ws, size_t ws_size,
                              hipStream_t stream) {
    const float* x    = (const float*)d_in[0];
    const float* W_ih = (const float*)d_in[1];
    const float* W_hh = (const float*)d_in[2];
    const float* b_ih = (const float*)d_in[3];
    const float* b_hh = (const float*)d_in[4];
    float* out = (float*)d_out;

    const int B = in_sizes[0] / (TSTEPS * INDIM);   // 4096
    const int grid = B / NBATCH;                    // 256 blocks, 1 per CU
    lstm_mfma<<<grid, 512, 0, stream>>>(x, W_ih, W_hh, b_ih, b_hh, out);
}